// Round 6
// baseline (121.315 us; speedup 1.0000x reference)
//
#include <hip/hip_runtime.h>

// 3D trilinear warp (grid_sample, align_corners=True, border padding).
// image: (B=2, 1, 160, 192, 192) f32 | ddf: (B,3,D,H,W) f32 (dz,dy,dx voxels)
//
// Round-6: LDS-staged gathers.
//  - 512-thread block, tile 32(x) x 8(y) x 8(z) = 2048 voxels, 4 vox/thread.
//  - Stage region 52x25x25 floats (130 KB LDS) = tile + halo 8/9, clamped
//    inside the volume (no bounds checks while staging; coalesced dwordx4).
//  - Gathers read LDS (banked, no L1 capacity misses). ~2% of voxels whose
//    corners fall outside the halo take an exec-masked global fallback.
//  - ddf loads issued before staging so HBM latency hides under it.
//  - XCD-chunked bijective block swizzle kept (5760 % 8 == 0).

typedef float f32x4 __attribute__((ext_vector_type(4)));
typedef float f32x2 __attribute__((ext_vector_type(2)));

constexpr int D_ = 160, H_ = 192, W_ = 192;
constexpr int HW_ = H_ * W_;
constexpr int N_ = D_ * HW_;
constexpr int NG_ = N_ / 4;

constexpr int TX_ = 32, TY_ = 8, TZ_ = 8;       // tile per block (2048 vox)
constexpr int XT_ = W_ / TX_;                   // 6
constexpr int YT_ = H_ / TY_;                   // 24
constexpr int ZT_ = D_ / TZ_;                   // 20
constexpr int TPB_ = XT_ * YT_ * ZT_;           // 2880 tiles/batch
constexpr int TOTAL_BLOCKS = 2 * TPB_;          // 5760 (%8 == 0)

constexpr int RX_ = 52, RY_ = 25, RZ_ = 25;     // staged region (floats)
constexpr int RSZ_ = RX_ * RY_ * RZ_;           // 32500 floats = 130 KB
constexpr int ROWS_ = RY_ * RZ_;                // 625
constexpr int CPR_ = RX_ / 4;                   // 13 dwordx4 chunks per row
constexpr int CHUNKS_ = CPR_ * ROWS_;           // 8125

__global__ __launch_bounds__(512) void warp3d_kernel(
    const float* __restrict__ img,
    const f32x4* __restrict__ ddf4,
    f32x4* __restrict__ out4)
{
    __shared__ float tile[RSZ_];

    constexpr int CPX = TOTAL_BLOCKS / 8;       // 720
    int bid = blockIdx.x;
    int swz = (bid % 8) * CPX + bid / 8;

    int b  = swz / TPB_;
    int t  = swz - b * TPB_;
    int tz = t / (XT_ * YT_);
    int r  = t - tz * (XT_ * YT_);
    int ty = r / XT_;
    int tx = r - ty * XT_;

    int tid = threadIdx.x;
    int xg = tid & 7;
    int yy = (tid >> 3) & 7;
    int zz = tid >> 6;

    int x = tx * TX_ + xg * 4;
    int y = ty * TY_ + yy;
    int z = tz * TZ_ + zz;
    int s  = (z * H_ + y) * W_ + x;
    int s4 = s >> 2;

    // region origin, clamped fully inside the volume
    int rx = min(max(tx * TX_ - 8, 0), W_ - RX_);
    int ry = min(max(ty * TY_ - 8, 0), H_ - RY_);
    int rz = min(max(tz * TZ_ - 8, 0), D_ - RZ_);

    const float* im = img + (size_t)b * N_;

    // ddf loads first: HBM latency hides under the staging phase
    const f32x4* dd = ddf4 + (size_t)b * 3 * NG_;
    f32x4 dzv = __builtin_nontemporal_load(dd + s4);
    f32x4 dyv = __builtin_nontemporal_load(dd + NG_ + s4);
    f32x4 dxv = __builtin_nontemporal_load(dd + 2 * NG_ + s4);

    // ---- stage region into LDS (coalesced dwordx4, no bounds checks) ----
    const float* rbase = im + (rz * H_ + ry) * W_ + rx;
#pragma unroll
    for (int k = 0; k < 16; ++k) {
        int c = tid + (k << 9);
        if (c < CHUNKS_) {
            int row = c / CPR_;              // magic-mul
            int xi  = c - row * CPR_;
            int zr  = row / RY_;
            int yr  = row - zr * RY_;
            f32x4 v = *(const f32x4*)(rbase + (zr * H_ + yr) * W_ + xi * 4);
            *(f32x4*)&tile[row * RX_ + xi * 4] = v;
        }
    }
    __syncthreads();

    // ---- per-voxel coords / weights / membership ----
    int   lo[4];     bool in[4];   int goff[4];
    float wx[4], wy[4], wz[4];
    float fy = (float)y, fz = (float)z;

#pragma unroll
    for (int i = 0; i < 4; ++i) {
        float ix = fminf(fmaxf((float)(x + i) + dxv[i], 0.0f), (float)(W_ - 1));
        float iy = fminf(fmaxf(fy + dyv[i], 0.0f), (float)(H_ - 1));
        float iz = fminf(fmaxf(fz + dzv[i], 0.0f), (float)(D_ - 1));

        int x0 = min((int)ix, W_ - 2);
        int y0 = min((int)iy, H_ - 2);
        int z0 = min((int)iz, D_ - 2);

        wx[i] = ix - (float)x0;
        wy[i] = iy - (float)y0;
        wz[i] = iz - (float)z0;

        int ux = x0 - rx, uy = y0 - ry, uz = z0 - rz;
        in[i] = ((unsigned)ux <= RX_ - 2) & ((unsigned)uy <= RY_ - 2)
              & ((unsigned)uz <= RZ_ - 2);

        int cux = min(max(ux, 0), RX_ - 2);
        int cuy = min(max(uy, 0), RY_ - 2);
        int cuz = min(max(uz, 0), RZ_ - 2);
        lo[i]   = (cuz * RY_ + cuy) * RX_ + cux;
        goff[i] = z0 * HW_ + y0 * W_ + x0;
    }

    // ---- LDS gathers (branchless; clamped offsets are always in-bounds) ----
    f32x2 v00[4], v01[4], v10[4], v11[4];
#pragma unroll
    for (int i = 0; i < 4; ++i) {
        int o = lo[i];
        v00[i] = f32x2{tile[o],               tile[o + 1]};
        v01[i] = f32x2{tile[o + RX_],         tile[o + RX_ + 1]};
        v10[i] = f32x2{tile[o + RX_ * RY_],   tile[o + RX_ * RY_ + 1]};
        v11[i] = f32x2{tile[o + RX_ * RY_ + RX_], tile[o + RX_ * RY_ + RX_ + 1]};
    }

    // ---- rare global fallback (exec-masked; ~2% of voxels) ----
#pragma unroll
    for (int i = 0; i < 4; ++i) {
        if (!in[i]) {
            const float* p = im + goff[i];
            v00[i] = *(const f32x2*)(p);
            v01[i] = *(const f32x2*)(p + W_);
            v10[i] = *(const f32x2*)(p + HW_);
            v11[i] = *(const f32x2*)(p + HW_ + W_);
        }
    }

    // ---- blend ----
    float res[4];
#pragma unroll
    for (int i = 0; i < 4; ++i) {
        float c00 = v00[i].x + (v00[i].y - v00[i].x) * wx[i];
        float c01 = v01[i].x + (v01[i].y - v01[i].x) * wx[i];
        float c10 = v10[i].x + (v10[i].y - v10[i].x) * wx[i];
        float c11 = v11[i].x + (v11[i].y - v11[i].x) * wx[i];
        float c0 = c00 + (c01 - c00) * wy[i];
        float c1 = c10 + (c11 - c10) * wy[i];
        res[i] = c0 + (c1 - c0) * wz[i];
    }

    f32x4 o = {res[0], res[1], res[2], res[3]};
    __builtin_nontemporal_store(o, out4 + (size_t)b * NG_ + s4);
}

extern "C" void kernel_launch(void* const* d_in, const int* in_sizes, int n_in,
                              void* d_out, int out_size, void* d_ws, size_t ws_size,
                              hipStream_t stream) {
    const float* img  = (const float*)d_in[0];
    const f32x4* ddf4 = (const f32x4*)d_in[1];
    f32x4*       out4 = (f32x4*)d_out;

    warp3d_kernel<<<TOTAL_BLOCKS, 512, 0, stream>>>(img, ddf4, out4);
}

// Round 7
// 100.964 us; speedup vs baseline: 1.2016x; 1.2016x over previous
//
#include <hip/hip_runtime.h>

// 3D trilinear warp (grid_sample, align_corners=True, border padding).
// image: (B=2, 1, 160, 192, 192) f32 | ddf: (B,3,D,H,W) f32 (dz,dy,dx voxels)
//
// Round-7: rolling-z LDS pipeline.
//  - Block = 32(x) x 8(y) xy-tile, marches a z-run of 80 in groups of 4 slices.
//  - Circular LDS window: 32 slices of 52x24 floats (156KB), slot = z & 31.
//    Readable window at group Z: slices [Z-8, Z+20); step stages [Z+20, Z+24)
//    concurrently into the 4 disjoint slots (28 read + 4 write = 32).
//  - Per step (one barrier): issue staging loads -> prefetch next ddf ->
//    compute 1024 voxels from LDS -> commit ds_writes (T14 async split).
//  - Corners outside window (~0.7%, N(0,3) tails) take exec-masked global
//    fallback reads (always correct).
//  - Grid 6x24x2(zhalf)x2(batch) = 576 blocks, 1024 threads, XCD-chunked
//    swizzle so y-adjacent tiles share xy-halo in their XCD's L2.

typedef float f32x4 __attribute__((ext_vector_type(4)));

constexpr int D_ = 160, H_ = 192, W_ = 192;
constexpr int HW_ = H_ * W_;
constexpr int N_  = D_ * HW_;

constexpr int TX_ = 32, TY_ = 8, SZ_ = 4;   // xy tile, z-group size
constexpr int XT_ = W_ / TX_;               // 6
constexpr int YT_ = H_ / TY_;               // 24
constexpr int ZH_ = 2;                      // z halves per volume
constexpr int ZRUN_ = D_ / ZH_;             // 80
constexpr int GRP_ = ZRUN_ / SZ_;           // 20 groups per block
constexpr int NBLK_ = XT_ * YT_ * ZH_ * 2;  // 576 (%8==0)

constexpr int RX_ = 52, RY_ = 24;           // staged xy region (floats)
constexpr int SLICE_ = RX_ * RY_;           // 1248 floats per slice
constexpr int NZ_ = 32;                     // circular slices (power of 2)
constexpr int CPS_ = SLICE_ / 4;            // 312 dwordx4 chunks per slice
constexpr int CPR_ = RX_ / 4;               // 13 chunks per row

__global__ __launch_bounds__(1024) void warp3d_kernel(
    const float* __restrict__ img,
    const float* __restrict__ ddf,
    float* __restrict__ out)
{
    __shared__ float tile[NZ_ * SLICE_];    // 159,744 B

    // XCD-chunked bijective swizzle (576 % 8 == 0); chunk of 72 = half the
    // xy tiles of one (zhalf,batch): tx 0..5 x ty run -> y-adjacent in L2.
    constexpr int CPX = NBLK_ / 8;          // 72
    int bid = blockIdx.x;
    int swz = (bid & 7) * CPX + (bid >> 3);

    int tx = swz % XT_;  int t1 = swz / XT_;
    int ty = t1 % YT_;   int t2 = t1 / YT_;
    int zh = t2 & 1;     int b  = t2 >> 1;

    int zlo = zh * ZRUN_;
    int rx = min(max(tx * TX_ - 8, 0), W_ - RX_);   // region x origin
    int ry = min(max(ty * TY_ - 7, 0), H_ - RY_);   // region y origin

    const float* im = img + (size_t)b * N_;
    const float* dp = ddf + (size_t)b * 3 * N_;
    float*       op = out + (size_t)b * N_;

    int tid = threadIdx.x;
    int xi = tid & 31;
    int yy = (tid >> 5) & 7;
    int zz = tid >> 8;                      // 0..3

    int x = tx * TX_ + xi;
    int y = ty * TY_ + yy;

    // ---- ddf prefetch for group 0 (hides under prologue staging) ----
    int s = ((zlo + zz) * H_ + y) * W_ + x;
    float cdz = __builtin_nontemporal_load(dp + s);
    float cdy = __builtin_nontemporal_load(dp + N_ + s);
    float cdx = __builtin_nontemporal_load(dp + 2 * N_ + s);

    // ---- prologue: stage slices [max(0,zlo-8), zlo+20) ----
    int pz0 = max(0, zlo - 8);
    int pcnt = (zlo + 20 - pz0) * CPS_;
    for (int c = tid; c < pcnt; c += 1024) {
        int si  = c / CPS_;
        int rem = c - si * CPS_;
        int zs  = pz0 + si;
        int row = rem / CPR_;
        int col = rem - row * CPR_;
        f32x4 v = *(const f32x4*)(im + (zs * H_ + ry + row) * W_ + rx + col * 4);
        *(f32x4*)&tile[(zs & (NZ_ - 1)) * SLICE_ + rem * 4] = v;
    }
    __syncthreads();

    for (int g = 0; g < GRP_; ++g) {
        int Z = zlo + g * SZ_;
        int z = Z + zz;

        // (a) issue staging loads for slices [Z+20, Z+24) into registers
        f32x4 sv0, sv1; int sl0, sl1; bool sm0, sm1;
        {
            int zfrom = Z + 20;
            int c0  = tid;                          // < 1248 always
            int si0 = c0 / CPS_;
            int rem0 = c0 - si0 * CPS_;
            int zs0 = zfrom + si0;
            sm0 = (zs0 < D_);
            sl0 = (zs0 & (NZ_ - 1)) * SLICE_ + rem0 * 4;
            if (sm0) {
                int row = rem0 / CPR_;
                int col = rem0 - row * CPR_;
                sv0 = *(const f32x4*)(im + (zs0 * H_ + ry + row) * W_ + rx + col * 4);
            }
            int c1  = tid + 1024;
            int si1 = c1 / CPS_;
            int rem1 = c1 - si1 * CPS_;
            int zs1 = zfrom + si1;
            sm1 = (c1 < SZ_ * CPS_) && (zs1 < D_);
            sl1 = (zs1 & (NZ_ - 1)) * SLICE_ + rem1 * 4;
            if (sm1) {
                int row = rem1 / CPR_;
                int col = rem1 - row * CPR_;
                sv1 = *(const f32x4*)(im + (zs1 * H_ + ry + row) * W_ + rx + col * 4);
            }
        }

        // (b) ddf prefetch for next group (uniform branch)
        float ndz = 0.f, ndy = 0.f, ndx = 0.f;
        if (g + 1 < GRP_) {
            int sn = s + SZ_ * HW_;
            ndz = __builtin_nontemporal_load(dp + sn);
            ndy = __builtin_nontemporal_load(dp + N_ + sn);
            ndx = __builtin_nontemporal_load(dp + 2 * N_ + sn);
        }

        // (c) compute this voxel from the LDS window
        {
            float ix = fminf(fmaxf((float)x + cdx, 0.f), (float)(W_ - 1));
            float iy = fminf(fmaxf((float)y + cdy, 0.f), (float)(H_ - 1));
            float iz = fminf(fmaxf((float)z + cdz, 0.f), (float)(D_ - 1));

            int x0 = min((int)ix, W_ - 2);
            int y0 = min((int)iy, H_ - 2);
            int z0 = min((int)iz, D_ - 2);
            float wx = ix - (float)x0;
            float wy = iy - (float)y0;
            float wz = iz - (float)z0;

            int ux = x0 - rx, uy = y0 - ry;
            bool inb = ((unsigned)ux <= (unsigned)(RX_ - 2)) &&
                       ((unsigned)uy <= (unsigned)(RY_ - 2)) &&
                       (z0 >= Z - 8) && (z0 <= Z + 18);

            float v000, v001, v010, v011, v100, v101, v110, v111;
            if (inb) {
                int base = uy * RX_ + ux;
                int o0 = (z0 & (NZ_ - 1)) * SLICE_ + base;
                int o1 = ((z0 + 1) & (NZ_ - 1)) * SLICE_ + base;
                v000 = tile[o0];        v001 = tile[o0 + 1];
                v010 = tile[o0 + RX_];  v011 = tile[o0 + RX_ + 1];
                v100 = tile[o1];        v101 = tile[o1 + 1];
                v110 = tile[o1 + RX_];  v111 = tile[o1 + RX_ + 1];
            } else {
                const float* p = im + (z0 * HW_ + y0 * W_ + x0);
                v000 = p[0];        v001 = p[1];
                v010 = p[W_];       v011 = p[W_ + 1];
                v100 = p[HW_];      v101 = p[HW_ + 1];
                v110 = p[HW_ + W_]; v111 = p[HW_ + W_ + 1];
            }

            float c00 = v000 + (v001 - v000) * wx;
            float c01 = v010 + (v011 - v010) * wx;
            float c10 = v100 + (v101 - v100) * wx;
            float c11 = v110 + (v111 - v110) * wx;
            float c0 = c00 + (c01 - c00) * wy;
            float c1 = c10 + (c11 - c10) * wy;
            __builtin_nontemporal_store(c0 + (c1 - c0) * wz, op + s);
        }

        // (d) commit staged slices to LDS (vmcnt waits land here)
        if (sm0) *(f32x4*)&tile[sl0] = sv0;
        if (sm1) *(f32x4*)&tile[sl1] = sv1;

        __syncthreads();

        cdz = ndz; cdy = ndy; cdx = ndx;
        s += SZ_ * HW_;
    }
}

extern "C" void kernel_launch(void* const* d_in, const int* in_sizes, int n_in,
                              void* d_out, int out_size, void* d_ws, size_t ws_size,
                              hipStream_t stream) {
    const float* img = (const float*)d_in[0];
    const float* ddf = (const float*)d_in[1];
    float*       out = (float*)d_out;

    warp3d_kernel<<<NBLK_, 1024, 0, stream>>>(img, ddf, out);
}

// Round 8
// 89.327 us; speedup vs baseline: 1.3581x; 1.1303x over previous
//
#include <hip/hip_runtime.h>

// 3D trilinear warp (grid_sample, align_corners=True, border padding).
// image: (B=2, 1, 160, 192, 192) f32 | ddf: (B,3,D,H,W) f32 (dz,dy,dx voxels)
//
// Round-8: rolling-z LDS pipeline + miss-queue epilogue.
//  - Block = 32(x) x 8(y) tile, z-run of 80 in groups of 8 slices (10 barriers).
//    1024 threads, 2 voxels/thread/group (z and z+4).
//  - Circular LDS window: 32 slices of 52x23 f32 (153KB), slot = z & 31.
//    At group base Z: safe-readable corner range z0 in [Z-4, Z+17]; this
//    group stages slices [Z+20, Z+28) (slots alias [Z-12, Z-4): disjoint).
//  - Main loop is branchless-LDS only. Out-of-window voxels (~2.6%) push
//    their linear index into an LDS queue (4KB); an epilogue pass re-reads
//    their ddf (L3-hot), gathers globally and stores. This removes the
//    divergent global fallback (and its vmcnt drain before ds_write commit)
//    from every group -- the R7 stall.
//  - Per group: issue 3 staging loads -> prefetch next ddf (6) -> compute
//    2 voxels from LDS -> ds_write commit -> predicated NT stores -> barrier.
//  - XCD-chunked bijective swizzle kept (576 % 8 == 0).

typedef float f32x4 __attribute__((ext_vector_type(4)));
typedef float f32x2 __attribute__((ext_vector_type(2)));

constexpr int D_ = 160, H_ = 192, W_ = 192;
constexpr int HW_ = H_ * W_;
constexpr int N_  = D_ * HW_;

constexpr int TX_ = 32, TY_ = 8, SZ_ = 8;
constexpr int XT_ = W_ / TX_;               // 6
constexpr int YT_ = H_ / TY_;               // 24
constexpr int ZH_ = 2;
constexpr int ZRUN_ = D_ / ZH_;             // 80
constexpr int GRP_ = ZRUN_ / SZ_;           // 10
constexpr int NBLK_ = XT_ * YT_ * ZH_ * 2;  // 576 (%8==0)

constexpr int RX_ = 52, RY_ = 23;           // staged xy region
constexpr int SLICE_ = RX_ * RY_;           // 1196 floats
constexpr int NZ_ = 32;                     // circular slices
constexpr int CPS_ = SLICE_ / 4;            // 299 dwordx4 chunks/slice
constexpr int CPR_ = RX_ / 4;               // 13 chunks/row
constexpr int GCH_ = SZ_ * CPS_;            // 2392 chunks/group
constexpr int QCAP_ = 1023;

__global__ __launch_bounds__(1024) void warp3d_kernel(
    const float* __restrict__ img,
    const float* __restrict__ ddf,
    float* __restrict__ out)
{
    __shared__ float tile[NZ_ * SLICE_];    // 153,088 B
    __shared__ int   qbuf[QCAP_];           // 4,092 B
    __shared__ int   qcount;

    constexpr int CPX = NBLK_ / 8;          // 72
    int bid = blockIdx.x;
    int swz = (bid & 7) * CPX + (bid >> 3);

    int tx = swz % XT_;  int t1 = swz / XT_;
    int ty = t1 % YT_;   int t2 = t1 / YT_;
    int zh = t2 & 1;     int b  = t2 >> 1;

    int zlo = zh * ZRUN_;
    int rx = min(max(tx * TX_ - 8, 0), W_ - RX_);
    int ry = min(max(ty * TY_ - 7, 0), H_ - RY_);

    const float* im = img + (size_t)b * N_;
    const float* dp = ddf + (size_t)b * 3 * N_;
    float*       op = out + (size_t)b * N_;

    int tid = threadIdx.x;
    int xi = tid & 31;
    int yy = (tid >> 5) & 7;
    int zz = tid >> 8;                      // 0..3

    int x = tx * TX_ + xi;
    int y = ty * TY_ + yy;

    int sA = ((zlo + zz) * H_ + y) * W_ + x;
    int sB = sA + 4 * HW_;

    // ddf prefetch for group 0 (latency hides under prologue staging)
    float cdzA = __builtin_nontemporal_load(dp + sA);
    float cdyA = __builtin_nontemporal_load(dp + N_ + sA);
    float cdxA = __builtin_nontemporal_load(dp + 2 * N_ + sA);
    float cdzB = __builtin_nontemporal_load(dp + sB);
    float cdyB = __builtin_nontemporal_load(dp + N_ + sB);
    float cdxB = __builtin_nontemporal_load(dp + 2 * N_ + sB);

    // ---- prologue: stage slices [max(0,zlo-4), zlo+20) ----
    int pz0 = max(0, zlo - 4);
    int pcnt = (zlo + 20 - pz0) * CPS_;
    for (int c = tid; c < pcnt; c += 1024) {
        int si  = c / CPS_;
        int rem = c - si * CPS_;
        int zs  = pz0 + si;
        int row = rem / CPR_;
        int col = rem - row * CPR_;
        f32x4 v = *(const f32x4*)(im + (zs * H_ + ry + row) * W_ + rx + col * 4);
        *(f32x4*)&tile[(zs & (NZ_ - 1)) * SLICE_ + rem * 4] = v;
    }
    if (tid == 0) qcount = 0;
    __syncthreads();

    // LDS compute for one voxel; sets miss if any corner outside safe window
    auto compute = [&](int z, float ddx, float ddy, float ddz,
                       int Z, bool& miss) -> float {
        float ix = fminf(fmaxf((float)x + ddx, 0.f), (float)(W_ - 1));
        float iy = fminf(fmaxf((float)y + ddy, 0.f), (float)(H_ - 1));
        float iz = fminf(fmaxf((float)z + ddz, 0.f), (float)(D_ - 1));
        int x0 = min((int)ix, W_ - 2);
        int y0 = min((int)iy, H_ - 2);
        int z0 = min((int)iz, D_ - 2);
        float wx = ix - (float)x0;
        float wy = iy - (float)y0;
        float wz = iz - (float)z0;

        int ux = x0 - rx, uy = y0 - ry, uz = z0 - (Z - 4);
        miss = !(((unsigned)ux <= (unsigned)(RX_ - 2)) &
                 ((unsigned)uy <= (unsigned)(RY_ - 2)) &
                 ((unsigned)uz <= 21u));

        int uxc = min(max(ux, 0), RX_ - 2);
        int uyc = min(max(uy, 0), RY_ - 2);
        int uzc = min(max(uz, 0), 21);
        int z0c = (Z - 4) + uzc;
        int base = uyc * RX_ + uxc;
        int o0 = (z0c & (NZ_ - 1)) * SLICE_ + base;
        int o1 = ((z0c + 1) & (NZ_ - 1)) * SLICE_ + base;

        float v000 = tile[o0];       float v001 = tile[o0 + 1];
        float v010 = tile[o0 + RX_]; float v011 = tile[o0 + RX_ + 1];
        float v100 = tile[o1];       float v101 = tile[o1 + 1];
        float v110 = tile[o1 + RX_]; float v111 = tile[o1 + RX_ + 1];

        float c00 = v000 + (v001 - v000) * wx;
        float c01 = v010 + (v011 - v010) * wx;
        float c10 = v100 + (v101 - v100) * wx;
        float c11 = v110 + (v111 - v110) * wx;
        float c0 = c00 + (c01 - c00) * wy;
        float c1 = c10 + (c11 - c10) * wy;
        return c0 + (c1 - c0) * wz;
    };

    // global gather (overflow-inline + epilogue path)
    auto gglobal = [&](int vx, int vy, int vz,
                       float ddx, float ddy, float ddz) -> float {
        float ix = fminf(fmaxf((float)vx + ddx, 0.f), (float)(W_ - 1));
        float iy = fminf(fmaxf((float)vy + ddy, 0.f), (float)(H_ - 1));
        float iz = fminf(fmaxf((float)vz + ddz, 0.f), (float)(D_ - 1));
        int x0 = min((int)ix, W_ - 2);
        int y0 = min((int)iy, H_ - 2);
        int z0 = min((int)iz, D_ - 2);
        float wx = ix - (float)x0;
        float wy = iy - (float)y0;
        float wz = iz - (float)z0;
        const float* p = im + (z0 * HW_ + y0 * W_ + x0);
        f32x2 a = *(const f32x2*)(p);
        f32x2 c = *(const f32x2*)(p + W_);
        f32x2 e = *(const f32x2*)(p + HW_);
        f32x2 f = *(const f32x2*)(p + HW_ + W_);
        float c00 = a.x + (a.y - a.x) * wx;
        float c01 = c.x + (c.y - c.x) * wx;
        float c10 = e.x + (e.y - e.x) * wx;
        float c11 = f.x + (f.y - f.x) * wx;
        float c0 = c00 + (c01 - c00) * wy;
        float c1 = c10 + (c11 - c10) * wy;
        return c0 + (c1 - c0) * wz;
    };

    for (int g = 0; g < GRP_; ++g) {
        int Z = zlo + g * SZ_;

        // (a) issue staging loads for slices [Z+20, Z+28)
        f32x4 sv0, sv1, sv2;
        int sl0, sl1, sl2;
        bool sm0, sm1, sm2;
        {
            int zfrom = Z + 20;
            int c0 = tid;
            int si0 = c0 / CPS_;  int rem0 = c0 - si0 * CPS_;
            int zs0 = zfrom + si0;
            sm0 = (zs0 < D_);
            sl0 = (zs0 & (NZ_ - 1)) * SLICE_ + rem0 * 4;
            if (sm0) {
                int row = rem0 / CPR_; int col = rem0 - row * CPR_;
                sv0 = *(const f32x4*)(im + (zs0 * H_ + ry + row) * W_ + rx + col * 4);
            }
            int c1 = tid + 1024;
            int si1 = c1 / CPS_;  int rem1 = c1 - si1 * CPS_;
            int zs1 = zfrom + si1;
            sm1 = (zs1 < D_);
            sl1 = (zs1 & (NZ_ - 1)) * SLICE_ + rem1 * 4;
            if (sm1) {
                int row = rem1 / CPR_; int col = rem1 - row * CPR_;
                sv1 = *(const f32x4*)(im + (zs1 * H_ + ry + row) * W_ + rx + col * 4);
            }
            int c2 = tid + 2048;
            int si2 = c2 / CPS_;  int rem2 = c2 - si2 * CPS_;
            int zs2 = zfrom + si2;
            sm2 = (c2 < GCH_) && (zs2 < D_);
            sl2 = (zs2 & (NZ_ - 1)) * SLICE_ + rem2 * 4;
            if (sm2) {
                int row = rem2 / CPR_; int col = rem2 - row * CPR_;
                sv2 = *(const f32x4*)(im + (zs2 * H_ + ry + row) * W_ + rx + col * 4);
            }
        }

        // (b) ddf prefetch for next group
        float ndzA = 0.f, ndyA = 0.f, ndxA = 0.f;
        float ndzB = 0.f, ndyB = 0.f, ndxB = 0.f;
        if (g + 1 < GRP_) {
            int snA = sA + SZ_ * HW_;
            int snB = sB + SZ_ * HW_;
            ndzA = __builtin_nontemporal_load(dp + snA);
            ndyA = __builtin_nontemporal_load(dp + N_ + snA);
            ndxA = __builtin_nontemporal_load(dp + 2 * N_ + snA);
            ndzB = __builtin_nontemporal_load(dp + snB);
            ndyB = __builtin_nontemporal_load(dp + N_ + snB);
            ndxB = __builtin_nontemporal_load(dp + 2 * N_ + snB);
        }

        // (c) compute 2 voxels from the LDS window (branchless reads)
        int zA = Z + zz, zB = Z + 4 + zz;
        bool missA, missB;
        float resA = compute(zA, cdxA, cdyA, cdzA, Z, missA);
        float resB = compute(zB, cdxB, cdyB, cdzB, Z, missB);

        // queue misses (rare); inline-gather only on queue overflow
        if (missA) {
            int idx = atomicAdd(&qcount, 1);
            if (idx < QCAP_) qbuf[idx] = sA;
            else { resA = gglobal(x, y, zA, cdxA, cdyA, cdzA); missA = false; }
        }
        if (missB) {
            int idx = atomicAdd(&qcount, 1);
            if (idx < QCAP_) qbuf[idx] = sB;
            else { resB = gglobal(x, y, zB, cdxB, cdyB, cdzB); missB = false; }
        }

        // (d) commit staged slices (vmcnt counts only staging+ddf loads)
        if (sm0) *(f32x4*)&tile[sl0] = sv0;
        if (sm1) *(f32x4*)&tile[sl1] = sv1;
        if (sm2) *(f32x4*)&tile[sl2] = sv2;

        // predicated output stores
        if (!missA) __builtin_nontemporal_store(resA, op + sA);
        if (!missB) __builtin_nontemporal_store(resB, op + sB);

        __syncthreads();

        cdzA = ndzA; cdyA = ndyA; cdxA = ndxA;
        cdzB = ndzB; cdyB = ndyB; cdxB = ndxB;
        sA += SZ_ * HW_;
        sB += SZ_ * HW_;
    }

    // ---- epilogue: resolve queued misses (globals; ddf re-read is L3-hot) ----
    int n = qcount;
    if (n > QCAP_) n = QCAP_;
    for (int i = tid; i < n; i += 1024) {
        int sq = qbuf[i];
        int zq = sq / HW_;
        int rq = sq - zq * HW_;
        int yq = rq / W_;
        int xq = rq - yq * W_;
        float qdz = dp[sq];
        float qdy = dp[N_ + sq];
        float qdx = dp[2 * N_ + sq];
        float res = gglobal(xq, yq, zq, qdx, qdy, qdz);
        op[sq] = res;
    }
}

extern "C" void kernel_launch(void* const* d_in, const int* in_sizes, int n_in,
                              void* d_out, int out_size, void* d_ws, size_t ws_size,
                              hipStream_t stream) {
    const float* img = (const float*)d_in[0];
    const float* ddf = (const float*)d_in[1];
    float*       out = (float*)d_out;

    warp3d_kernel<<<NBLK_, 1024, 0, stream>>>(img, ddf, out);
}

// Round 9
// 87.471 us; speedup vs baseline: 1.3869x; 1.0212x over previous
//
#include <hip/hip_runtime.h>

// 3D trilinear warp (grid_sample, align_corners=True, border padding).
// image: (B=2, 1, 160, 192, 192) f32 | ddf: (B,3,D,H,W) f32 (dz,dy,dx voxels)
//
// Round-9: one-shot LDS window + perfectly balanced grid.
//  - Grid 6(x) x 24(y) x 8(zh) x 2(b) = 2304 blocks = exactly 9 per CU.
//  - Block = 32x8 xy-tile, z-run of 20. Staged window: slices
//    [zlo-4, zlo+28) of a 52x23 xy region = 32 slices x 1196 f = 153 KB,
//    slot = z & 31 (bijective over the 32-slice range). Staged ONCE.
//  - Compute: 5 voxels/thread, straight-line, branchless LDS reads
//    (clamped offsets; garbage reads for misses are discarded). Only 2
//    barriers per block (post-stage, pre-epilogue).
//  - Misses (~1.5%: window halo x -8/+11, y -7/+8, z -4..-1 rows only)
//    push {s, dx, dy, dz} into an LDS queue (float4, 8KB) -> epilogue
//    gathers them from global (L2-hot) WITHOUT re-reading ddf from HBM.
//  - XCD-chunked bijective swizzle: chunk of 288 = 2 adjacent z-runs of one
//    batch, all xy tiles -> XCD's L2 holds a contiguous slab; concurrent
//    blocks are xy-neighbors sharing halo lines.

typedef float f32x4 __attribute__((ext_vector_type(4)));
typedef float f32x2 __attribute__((ext_vector_type(2)));

constexpr int D_ = 160, H_ = 192, W_ = 192;
constexpr int HW_ = H_ * W_;
constexpr int N_  = D_ * HW_;

constexpr int TX_ = 32, TY_ = 8;
constexpr int XT_ = W_ / TX_;               // 6
constexpr int YT_ = H_ / TY_;               // 24
constexpr int ZH_ = 8;
constexpr int ZRUN_ = D_ / ZH_;             // 20
constexpr int NBLK_ = XT_ * YT_ * ZH_ * 2;  // 2304 = 9 * 256 exactly

constexpr int RX_ = 52, RY_ = 23;
constexpr int SLICE_ = RX_ * RY_;           // 1196 floats (4784 B, 16-aligned)
constexpr int NZ_ = 32;
constexpr int CPS_ = SLICE_ / 4;            // 299 dwordx4 chunks per slice
constexpr int CPR_ = RX_ / 4;               // 13 chunks per row
constexpr int QCAP_ = 512;                  // mean ~77 misses/block, +48 sigma

__global__ __launch_bounds__(1024) void warp3d_kernel(
    const float* __restrict__ img,
    const float* __restrict__ ddf,
    float* __restrict__ out)
{
    __shared__ float tile[NZ_ * SLICE_];    // 153,088 B
    __shared__ f32x4 qdat[QCAP_];           // 8,192 B
    __shared__ int   qcount;

    constexpr int CPX = NBLK_ / 8;          // 288
    int bid = blockIdx.x;
    int swz = (bid & 7) * CPX + (bid >> 3);

    int tx = swz % XT_;  int t1 = swz / XT_;
    int ty = t1 % YT_;   int t2 = t1 / YT_;
    int zh = t2 % ZH_;   int b  = t2 / ZH_;

    int zlo = zh * ZRUN_;
    int rx = min(max(tx * TX_ - 8, 0), W_ - RX_);   // %4==0 in all cases
    int ry = min(max(ty * TY_ - 7, 0), H_ - RY_);

    const float* im = img + (size_t)b * N_;
    const float* dp = ddf + (size_t)b * 3 * N_;
    float*       op = out + (size_t)b * N_;

    int tid = threadIdx.x;
    int xi = tid & 31;
    int yy = (tid >> 5) & 7;
    int zz = tid >> 8;                      // 0..3

    int x = tx * TX_ + xi;
    int y = ty * TY_ + yy;
    int s0 = ((zlo + zz) * H_ + y) * W_ + x;

    // ---- ddf loads for all 5 voxels (HBM latency hides under staging) ----
    float ddz[5], ddy[5], ddx[5];
#pragma unroll
    for (int k = 0; k < 5; ++k) {
        int s = s0 + k * 4 * HW_;
        ddz[k] = __builtin_nontemporal_load(dp + s);
        ddy[k] = __builtin_nontemporal_load(dp + N_ + s);
        ddx[k] = __builtin_nontemporal_load(dp + 2 * N_ + s);
    }

    // ---- one-shot staging of slices [max(0,zlo-4), min(D,zlo+28)) ----
    if (tid == 0) qcount = 0;
    int pz0 = max(0, zlo - 4);
    int pz1 = min(D_, zlo + 28);
    int pcnt = (pz1 - pz0) * CPS_;
    for (int c = tid; c < pcnt; c += 1024) {
        int si  = c / CPS_;
        int rem = c - si * CPS_;
        int zs  = pz0 + si;
        int row = rem / CPR_;
        int col = rem - row * CPR_;
        f32x4 v = *(const f32x4*)(im + (zs * H_ + ry + row) * W_ + rx + col * 4);
        *(f32x4*)&tile[(zs & (NZ_ - 1)) * SLICE_ + rem * 4] = v;
    }
    __syncthreads();

    // global gather (overflow + epilogue path)
    auto gglobal = [&](int vx, int vy, int vz,
                       float gdx, float gdy, float gdz) -> float {
        float ix = fminf(fmaxf((float)vx + gdx, 0.f), (float)(W_ - 1));
        float iy = fminf(fmaxf((float)vy + gdy, 0.f), (float)(H_ - 1));
        float iz = fminf(fmaxf((float)vz + gdz, 0.f), (float)(D_ - 1));
        int x0 = min((int)ix, W_ - 2);
        int y0 = min((int)iy, H_ - 2);
        int z0 = min((int)iz, D_ - 2);
        float wx = ix - (float)x0;
        float wy = iy - (float)y0;
        float wz = iz - (float)z0;
        const float* p = im + (z0 * HW_ + y0 * W_ + x0);
        f32x2 a = *(const f32x2*)(p);
        f32x2 c = *(const f32x2*)(p + W_);
        f32x2 e = *(const f32x2*)(p + HW_);
        f32x2 f = *(const f32x2*)(p + HW_ + W_);
        float c00 = a.x + (a.y - a.x) * wx;
        float c01 = c.x + (c.y - c.x) * wx;
        float c10 = e.x + (e.y - e.x) * wx;
        float c11 = f.x + (f.y - f.x) * wx;
        float c0 = c00 + (c01 - c00) * wy;
        float c1 = c10 + (c11 - c10) * wy;
        return c0 + (c1 - c0) * wz;
    };

    // ---- straight-line compute: 5 voxels/thread, no barriers ----
#pragma unroll
    for (int k = 0; k < 5; ++k) {
        int z = zlo + zz + 4 * k;
        int s = s0 + k * 4 * HW_;

        float ix = fminf(fmaxf((float)x + ddx[k], 0.f), (float)(W_ - 1));
        float iy = fminf(fmaxf((float)y + ddy[k], 0.f), (float)(H_ - 1));
        float iz = fminf(fmaxf((float)z + ddz[k], 0.f), (float)(D_ - 1));

        int x0 = min((int)ix, W_ - 2);
        int y0 = min((int)iy, H_ - 2);
        int z0 = min((int)iz, D_ - 2);
        float wx = ix - (float)x0;
        float wy = iy - (float)y0;
        float wz = iz - (float)z0;

        int ux = x0 - rx, uy = y0 - ry, uz = z0 - (zlo - 4);
        bool in = ((unsigned)ux <= (unsigned)(RX_ - 2)) &
                  ((unsigned)uy <= (unsigned)(RY_ - 2)) &
                  ((unsigned)uz <= 30u);

        // branchless LDS read (clamped; garbage when !in, discarded)
        int uxc = min(max(ux, 0), RX_ - 2);
        int uyc = min(max(uy, 0), RY_ - 2);
        int uzc = min(max(uz, 0), 30);
        int z0c = (zlo - 4) + uzc;
        int base = uyc * RX_ + uxc;
        int o0 = (z0c & (NZ_ - 1)) * SLICE_ + base;
        int o1 = ((z0c + 1) & (NZ_ - 1)) * SLICE_ + base;

        float v000 = tile[o0];       float v001 = tile[o0 + 1];
        float v010 = tile[o0 + RX_]; float v011 = tile[o0 + RX_ + 1];
        float v100 = tile[o1];       float v101 = tile[o1 + 1];
        float v110 = tile[o1 + RX_]; float v111 = tile[o1 + RX_ + 1];

        float c00 = v000 + (v001 - v000) * wx;
        float c01 = v010 + (v011 - v010) * wx;
        float c10 = v100 + (v101 - v100) * wx;
        float c11 = v110 + (v111 - v110) * wx;
        float c0 = c00 + (c01 - c00) * wy;
        float c1 = c10 + (c11 - c10) * wy;
        float res = c0 + (c1 - c0) * wz;

        bool do_store = in;
        if (!in) {
            int idx = atomicAdd(&qcount, 1);
            if (idx < QCAP_) {
                qdat[idx] = f32x4{__int_as_float(s), ddx[k], ddy[k], ddz[k]};
            } else {
                res = gglobal(x, y, z, ddx[k], ddy[k], ddz[k]);
                do_store = true;
            }
        }
        if (do_store) __builtin_nontemporal_store(res, op + s);
    }

    __syncthreads();

    // ---- epilogue: resolve queued misses (ddf from queue, gathers L2-hot) --
    int n = min(qcount, QCAP_);
    for (int i = tid; i < n; i += 1024) {
        f32x4 q = qdat[i];
        int sq = __float_as_int(q.x);
        int zq = sq / HW_;
        int rq = sq - zq * HW_;
        int yq = rq / W_;
        int xq = rq - yq * W_;
        float res = gglobal(xq, yq, zq, q.y, q.z, q.w);
        op[sq] = res;
    }
}

extern "C" void kernel_launch(void* const* d_in, const int* in_sizes, int n_in,
                              void* d_out, int out_size, void* d_ws, size_t ws_size,
                              hipStream_t stream) {
    const float* img = (const float*)d_in[0];
    const float* ddf = (const float*)d_in[1];
    float*       out = (float*)d_out;

    warp3d_kernel<<<NBLK_, 1024, 0, stream>>>(img, ddf, out);
}